// Round 2
// baseline (3833.921 us; speedup 1.0000x reference)
//
#include <hip/hip_runtime.h>

// ---------------------------------------------------------------------------
// StyleGAN2 SynthesisBlock: B=16, H=W=64, C_IN=256, C_OUT=128, W_DIM=128
// out = pixel_shuffle(lrelu(modconv2(lrelu(modconv1(x,s1)+n1*ns1+b1), s2)+n2*ns2+b2))
//
// modconv(x, kernel, s) == demod[b,o] * conv2d(x * s[b,i], kernel)
//   demod[b,o] = rsqrt( sum_i s[b,i]^2 * ksq[i,o] + 1e-8 ),  ksq = sum_t k^2
// fp32 baseline: implicit-GEMM (M=4096 rows of 64 px, N=COUT, K=9*256),
// 64x64 LDS tiles, 4x4 acc/thread. Anchor for later MFMA rounds.
// ---------------------------------------------------------------------------

#define CIN 256

__global__ __launch_bounds__(256) void style_kernel(
    const float* __restrict__ w, const float* __restrict__ a1w, const float* __restrict__ a1b,
    const float* __restrict__ a2w, const float* __restrict__ a2b,
    float* __restrict__ s1, float* __restrict__ s2)
{
  const int b = blockIdx.x, c = threadIdx.x;
  const float* wb = w + b * 128;
  float acc1 = 0.f, acc2 = 0.f;
  for (int k = 0; k < 128; ++k) {
    const float wv = wb[k];
    acc1 = fmaf(wv, a1w[k * 256 + c], acc1);
    acc2 = fmaf(wv, a2w[k * 256 + c], acc2);
  }
  s1[b * 256 + c] = acc1 + a1b[c];
  s2[b * 256 + c] = acc2 + a2b[c];
}

__global__ __launch_bounds__(256) void ksq_kernel(
    const float* __restrict__ kern, float* __restrict__ ksq, int n)
{
  const int i = blockIdx.x * 256 + threadIdx.x;
  if (i < n) {
    float acc = 0.f;
    for (int t = 0; t < 9; ++t) { const float v = kern[t * n + i]; acc = fmaf(v, v, acc); }
    ksq[i] = acc;
  }
}

__global__ __launch_bounds__(256) void demod_kernel(
    const float* __restrict__ s, const float* __restrict__ ksq,
    float* __restrict__ demod, int cout)
{
  const int b = blockIdx.y;
  const int o = blockIdx.x * 256 + threadIdx.x;
  const float* sb = s + b * 256;
  float acc = 1e-8f;
  for (int i = 0; i < 256; ++i) {
    const float sv = sb[i];
    acc = fmaf(sv * sv, ksq[i * cout + o], acc);
  }
  demod[b * cout + o] = 1.0f / sqrtf(acc);
}

// Implicit-GEMM modulated conv + fused epilogue.
//   M-tile: one image row (b,y), 64 positions. N-tile: 64 output channels.
//   K = 9 taps x 256 in-ch, staged in 64-ch chunks.
//   A staged TRANSPOSED: As[kk][pos]; B: Bs[kk][n].
//   Epilogue: v = acc*demod + noise*ns + bias; lrelu(0.2); optional pixel-shuffle.
template <int COUT, bool SHUFFLE>
__global__ __launch_bounds__(256) void conv_kernel(
    const float* __restrict__ X,    // [16,64,64,CIN]
    const float* __restrict__ S,    // [16,CIN]
    const float* __restrict__ Kw,   // [9,CIN,COUT]
    const float* __restrict__ D,    // [16,COUT]
    const float* __restrict__ NZ,   // [16,64,64,1]
    const float* __restrict__ NSp,  // [1]
    const float* __restrict__ BIAS, // [COUT]
    float* __restrict__ OUT)        // [16,64,64,COUT] or shuffled [16,128,128,COUT/4]
{
  __shared__ float As[64][68];
  __shared__ float Bs[64][68];
  __shared__ float Ss[256];

  const int t  = threadIdx.x;
  const int row = blockIdx.x;           // b*64 + y
  const int b  = row >> 6, y = row & 63;
  const int o0 = blockIdx.y * 64;

  Ss[t] = S[b * 256 + t];               // covered by first __syncthreads in loop

  const int tx = t & 15, ty = t >> 4;
  const int schq  = t & 15;             // A staging: channel quad
  const int sposg = t >> 4;             // A staging: position group

  float acc[4][4] = {{0.f,0.f,0.f,0.f},{0.f,0.f,0.f,0.f},{0.f,0.f,0.f,0.f},{0.f,0.f,0.f,0.f}};

  const float* Xb = X + (size_t)b * (64 * 64 * CIN);

  for (int tap = 0; tap < 9; ++tap) {
    const int dy = tap / 3 - 1, dx = tap % 3 - 1;
    const int ys = y + dy;
    const bool vrow = ((unsigned)ys < 64u);
    const float* Xrow = Xb + ys * 64 * CIN;
    const float* Kt = Kw + (size_t)tap * CIN * COUT + o0;

    for (int c0 = 0; c0 < CIN; c0 += 64) {
      __syncthreads();
      #pragma unroll
      for (int j = 0; j < 4; ++j) {
        const int pos = sposg * 4 + j;
        const int xs = pos + dx;
        const bool v = vrow && ((unsigned)xs < 64u);
        float4 val = make_float4(0.f, 0.f, 0.f, 0.f);
        if (v) val = *(const float4*)(Xrow + xs * CIN + c0 + schq * 4);
        const float4 sv = *(const float4*)(Ss + c0 + schq * 4);
        const int ch = schq * 4;
        As[ch + 0][pos] = val.x * sv.x;
        As[ch + 1][pos] = val.y * sv.y;
        As[ch + 2][pos] = val.z * sv.z;
        As[ch + 3][pos] = val.w * sv.w;
      }
      #pragma unroll
      for (int j = 0; j < 4; ++j) {
        const int kk = (t >> 4) + j * 16;
        *(float4*)(&Bs[kk][(t & 15) * 4]) =
            *(const float4*)(Kt + (size_t)(c0 + kk) * COUT + (t & 15) * 4);
      }
      __syncthreads();
      #pragma unroll 16
      for (int kk = 0; kk < 64; ++kk) {
        const float4 a  = *(const float4*)(&As[kk][ty * 4]);
        const float4 bb = *(const float4*)(&Bs[kk][tx * 4]);
        const float av[4] = {a.x, a.y, a.z, a.w};
        const float bv[4] = {bb.x, bb.y, bb.z, bb.w};
        #pragma unroll
        for (int i = 0; i < 4; ++i)
          #pragma unroll
          for (int j = 0; j < 4; ++j)
            acc[i][j] = fmaf(av[i], bv[j], acc[i][j]);
      }
    }
  }

  const float ns = NSp[0];
  const float4 d4 = *(const float4*)(D + b * COUT + o0 + tx * 4);
  const float4 bi4 = *(const float4*)(BIAS + o0 + tx * 4);
  const float dv[4] = {d4.x, d4.y, d4.z, d4.w};
  const float bv[4] = {bi4.x, bi4.y, bi4.z, bi4.w};

  #pragma unroll
  for (int i = 0; i < 4; ++i) {
    const int pos = ty * 4 + i;
    const float nz = NZ[(b * 64 + y) * 64 + pos] * ns;
    float vv[4];
    #pragma unroll
    for (int j = 0; j < 4; ++j) {
      float v = fmaf(acc[i][j], dv[j], nz + bv[j]);
      vv[j] = fmaxf(v, 0.2f * v);  // leaky_relu(0.2)
    }
    const float4 v4 = make_float4(vv[0], vv[1], vv[2], vv[3]);
    if (!SHUFFLE) {
      *(float4*)(&OUT[((size_t)(b * 64 + y) * 64 + pos) * COUT + o0 + tx * 4]) = v4;
    } else {
      // full channel o = sh*256 + sw*128 + c  ->  out[b, 2y+sh, 2x+sw, c]
      const int o = o0 + tx * 4;
      const int g = o >> 7, c = o & 127;
      const int sh = g >> 1, sw = g & 1;
      *(float4*)(&OUT[(((size_t)(b * 128) + 2 * y + sh) * 128 + (2 * pos + sw)) * 128 + c]) = v4;
    }
  }
}

extern "C" void kernel_launch(void* const* d_in, const int* in_sizes, int n_in,
                              void* d_out, int out_size, void* d_ws, size_t ws_size,
                              hipStream_t stream)
{
  const float* x   = (const float*)d_in[0];
  const float* w   = (const float*)d_in[1];
  const float* a1w = (const float*)d_in[2];
  const float* a1b = (const float*)d_in[3];
  const float* k1  = (const float*)d_in[4];
  const float* ns1 = (const float*)d_in[5];
  const float* b1  = (const float*)d_in[6];
  const float* a2w = (const float*)d_in[7];
  const float* a2b = (const float*)d_in[8];
  const float* k2  = (const float*)d_in[9];
  const float* ns2 = (const float*)d_in[10];
  const float* b2  = (const float*)d_in[11];
  const float* nz1 = (const float*)d_in[12];
  const float* nz2 = (const float*)d_in[13];
  float* out = (float*)d_out;

  float* ws = (float*)d_ws;
  float* s1   = ws;              // [16,256]
  float* s2   = ws + 4096;       // [16,256]
  float* ksq1 = ws + 8192;       // [256,256]
  float* ksq2 = ws + 73728;      // [256,512]
  float* dm1  = ws + 204800;     // [16,256]
  float* dm2  = ws + 208896;     // [16,512]
  float* h    = ws + 217088;     // [16,64,64,256] = 64 MiB

  style_kernel<<<16, 256, 0, stream>>>(w, a1w, a1b, a2w, a2b, s1, s2);
  ksq_kernel<<<65536 / 256, 256, 0, stream>>>(k1, ksq1, 65536);
  ksq_kernel<<<131072 / 256, 256, 0, stream>>>(k2, ksq2, 131072);
  demod_kernel<<<dim3(1, 16), 256, 0, stream>>>(s1, ksq1, dm1, 256);
  demod_kernel<<<dim3(2, 16), 256, 0, stream>>>(s2, ksq2, dm2, 512);

  conv_kernel<256, false><<<dim3(1024, 4), 256, 0, stream>>>(x, s1, k1, dm1, nz1, ns1, b1, h);
  conv_kernel<512, true ><<<dim3(1024, 8), 256, 0, stream>>>(h, s2, k2, dm2, nz2, ns2, b2, out);
}

// Round 5
// 696.914 us; speedup vs baseline: 5.5013x; 5.5013x over previous
//
#include <hip/hip_runtime.h>
#include <type_traits>

// ---------------------------------------------------------------------------
// StyleGAN2 SynthesisBlock, MFMA f16 version.
//   modconv(x, kernel, s) == demod[b,o] * conv2d(x * s[b,i], kernel)
//   demod[b,o] = rsqrt( sum_i s[b,i]^2 * ksq[i,o] + 1e-8 )
// Conv as implicit GEMM, M=4096 rows of 64 px, K=9*256, f16 inputs, f32 accum
// via v_mfma_f32_16x16x32_f16. A staged with 66-px x-halo shared by 3 dx taps.
// ---------------------------------------------------------------------------

#define CIN 256

typedef _Float16 half4 __attribute__((ext_vector_type(4)));
typedef _Float16 half8 __attribute__((ext_vector_type(8)));
typedef float f32x4 __attribute__((ext_vector_type(4)));

__global__ __launch_bounds__(256) void style_kernel(
    const float* __restrict__ w, const float* __restrict__ a1w, const float* __restrict__ a1b,
    const float* __restrict__ a2w, const float* __restrict__ a2b,
    float* __restrict__ s1, float* __restrict__ s2)
{
  const int b = blockIdx.x, c = threadIdx.x;
  const float* wb = w + b * 128;
  float acc1 = 0.f, acc2 = 0.f;
  for (int k = 0; k < 128; ++k) {
    const float wv = wb[k];
    acc1 = fmaf(wv, a1w[k * 256 + c], acc1);
    acc2 = fmaf(wv, a2w[k * 256 + c], acc2);
  }
  s1[b * 256 + c] = acc1 + a1b[c];
  s2[b * 256 + c] = acc2 + a2b[c];
}

__global__ __launch_bounds__(256) void ksq_kernel(
    const float* __restrict__ kern, float* __restrict__ ksq, int n)
{
  const int i = blockIdx.x * 256 + threadIdx.x;
  if (i < n) {
    float acc = 0.f;
    for (int t = 0; t < 9; ++t) { const float v = kern[t * n + i]; acc = fmaf(v, v, acc); }
    ksq[i] = acc;
  }
}

__global__ __launch_bounds__(256) void demod_kernel(
    const float* __restrict__ s, const float* __restrict__ ksq,
    float* __restrict__ demod, int cout)
{
  const int b = blockIdx.y;
  const int o = blockIdx.x * 256 + threadIdx.x;
  const float* sb = s + b * 256;
  float acc = 1e-8f;
  for (int i = 0; i < 256; ++i) {
    const float sv = sb[i];
    acc = fmaf(sv * sv, ksq[i * cout + o], acc);
  }
  demod[b * cout + o] = 1.0f / sqrtf(acc);
}

// Kw[9][CIN][COUT] f32  ->  Bt[9][COUT][CIN] f16   (per-tap transpose + convert)
__global__ __launch_bounds__(256) void kprep_kernel(
    const float* __restrict__ Kw, _Float16* __restrict__ Bt, int cout)
{
  __shared__ float T[64][68];
  const int tap = blockIdx.z;
  const int o0 = blockIdx.x * 64, c0 = blockIdx.y * 64;
  const int t = threadIdx.x;
  #pragma unroll
  for (int it = 0; it < 4; ++it) {
    const int c = (t >> 4) + it * 16;
    const int o = (t & 15) * 4;
    *(float4*)(&T[c][o]) = *(const float4*)(Kw + ((size_t)tap * CIN + c0 + c) * cout + o0 + o);
  }
  __syncthreads();
  #pragma unroll
  for (int it = 0; it < 4; ++it) {
    const int o = (t >> 4) + it * 16;
    const int c = (t & 15) * 4;
    half4 hv = {(_Float16)T[c][o], (_Float16)T[c + 1][o],
                (_Float16)T[c + 2][o], (_Float16)T[c + 3][o]};
    *(half4*)(&Bt[((size_t)tap * cout + o0 + o) * CIN + c0 + c]) = hv;
  }
}

// MFMA implicit-GEMM modulated conv + fused epilogue.
// Block: M=64 px (one b,y row), N=64 out-ch. 4 waves (2Mx2N), wave = 32x32
// via 2x2 fragments of v_mfma_f32_16x16x32_f16.
// A: As[66][72] f16, x-halo rows (xs=-1..64), K-padded +8 -> no 16-way conflicts.
// B: Bs[3][64][72] f16 (n-major, k contiguous), all 3 dx taps of current dy.
template <int COUT, bool SHUFFLE, typename TIN, typename TOUT>
__global__ __launch_bounds__(256) void conv_mfma(
    const TIN* __restrict__ X,       // [16,64,64,CIN]
    const float* __restrict__ S,     // [16,CIN]
    const _Float16* __restrict__ Bt, // [9,COUT,CIN] f16
    const float* __restrict__ D,     // [16,COUT]
    const float* __restrict__ NZ,    // [16,64,64,1]
    const float* __restrict__ NSp,   // [1]
    const float* __restrict__ BIAS,  // [COUT]
    TOUT* __restrict__ OUT)          // [16,64,64,COUT] or shuffled [16,128,128,128]
{
  __shared__ __align__(16) _Float16 As[66][72];
  __shared__ __align__(16) _Float16 Bs[3][64][72];
  __shared__ float Ss[256];

  const int t = threadIdx.x;
  const int row = blockIdx.x;          // b*64 + y
  const int b = row >> 6, y = row & 63;
  const int o0 = blockIdx.y * 64;

  Ss[t] = S[b * 256 + t];              // covered by first __syncthreads in loop

  const int lane = t & 63, wid = t >> 6;
  const int wm = wid >> 1, wn = wid & 1;   // wave quadrant
  const int lrow = lane >> 4;              // 0..3 (k-octet / D row group)
  const int lcol = lane & 15;

  f32x4 acc[2][2];
  #pragma unroll
  for (int m = 0; m < 2; ++m)
    #pragma unroll
    for (int n = 0; n < 2; ++n)
      acc[m][n] = (f32x4){0.f, 0.f, 0.f, 0.f};

  const TIN* Xb = X + (size_t)b * (64 * 64 * CIN);

  for (int dyi = 0; dyi < 3; ++dyi) {
    const int ys = y + dyi - 1;
    const bool vrow = ((unsigned)ys < 64u);
    const TIN* Xrow = Xb + (size_t)ys * (64 * CIN);

    for (int c0 = 0; c0 < CIN; c0 += 64) {
      __syncthreads();  // protect previous chunk's fragment reads
      // ---- stage A: 66 halo rows (xs = -1..64), modulated, f16
      #pragma unroll
      for (int it = 0; it < 5; ++it) {
        const int r = (t >> 4) + it * 16;
        if (r < 66) {
          const int xs = r - 1;
          const int cq = (t & 15) * 4;
          half4 hv = {(_Float16)0, (_Float16)0, (_Float16)0, (_Float16)0};
          if (vrow && (unsigned)xs < 64u) {
            const float4 sv = *(const float4*)(Ss + c0 + cq);
            if constexpr (std::is_same_v<TIN, float>) {
              const float4 xv = *(const float4*)(Xrow + (size_t)xs * CIN + c0 + cq);
              hv[0] = (_Float16)(xv.x * sv.x);
              hv[1] = (_Float16)(xv.y * sv.y);
              hv[2] = (_Float16)(xv.z * sv.z);
              hv[3] = (_Float16)(xv.w * sv.w);
            } else {
              const half4 xv = *(const half4*)(Xrow + (size_t)xs * CIN + c0 + cq);
              hv[0] = (_Float16)((float)xv[0] * sv.x);
              hv[1] = (_Float16)((float)xv[1] * sv.y);
              hv[2] = (_Float16)((float)xv[2] * sv.z);
              hv[3] = (_Float16)((float)xv[3] * sv.w);
            }
          }
          *(half4*)(&As[r][cq]) = hv;
        }
      }
      // ---- stage B: 3 dx taps, Bs[dxi][n][k] (already f16, straight copy)
      #pragma unroll
      for (int dxi = 0; dxi < 3; ++dxi) {
        const int tap = dyi * 3 + dxi;
        const _Float16* Bsrc = Bt + ((size_t)tap * COUT + o0) * CIN + c0;
        #pragma unroll
        for (int it = 0; it < 2; ++it) {
          const int n = (t >> 3) + it * 32;
          const int hq = (t & 7) * 8;
          *(half8*)(&Bs[dxi][n][hq]) = *(const half8*)(Bsrc + (size_t)n * CIN + hq);
        }
      }
      __syncthreads();
      // ---- MFMA: 3 dx taps x 2 K-steps x (2x2 frags)
      #pragma unroll
      for (int dxi = 0; dxi < 3; ++dxi) {
        const int abase = dxi + wm * 32 + lcol;   // As row = p + dx + 1
        #pragma unroll
        for (int ks = 0; ks < 2; ++ks) {
          const int ko = ks * 32 + lrow * 8;
          const half8 a0 = *(const half8*)(&As[abase][ko]);
          const half8 a1 = *(const half8*)(&As[abase + 16][ko]);
          const half8 b0 = *(const half8*)(&Bs[dxi][wn * 32 + lcol][ko]);
          const half8 b1 = *(const half8*)(&Bs[dxi][wn * 32 + 16 + lcol][ko]);
          acc[0][0] = __builtin_amdgcn_mfma_f32_16x16x32_f16(a0, b0, acc[0][0], 0, 0, 0);
          acc[0][1] = __builtin_amdgcn_mfma_f32_16x16x32_f16(a0, b1, acc[0][1], 0, 0, 0);
          acc[1][0] = __builtin_amdgcn_mfma_f32_16x16x32_f16(a1, b0, acc[1][0], 0, 0, 0);
          acc[1][1] = __builtin_amdgcn_mfma_f32_16x16x32_f16(a1, b1, acc[1][1], 0, 0, 0);
        }
      }
    }
  }

  // ---- epilogue: D layout col = lane&15, row = (lane>>4)*4 + r  [m89-verified]
  const float ns = NSp[0];
  #pragma unroll
  for (int n = 0; n < 2; ++n) {
    const int o = o0 + wn * 32 + n * 16 + lcol;
    const float dmv = D[b * COUT + o];
    const float bv = BIAS[o];
    #pragma unroll
    for (int m = 0; m < 2; ++m) {
      #pragma unroll
      for (int r = 0; r < 4; ++r) {
        const int p = wm * 32 + m * 16 + lrow * 4 + r;   // output x
        const float nzv = NZ[(size_t)(b * 64 + y) * 64 + p] * ns;
        float v = fmaf(acc[m][n][r], dmv, nzv + bv);
        v = fmaxf(v, 0.2f * v);                          // leaky_relu(0.2)
        if (!SHUFFLE) {
          OUT[((size_t)(b * 64 + y) * 64 + p) * COUT + o] = (TOUT)v;
        } else {
          // o = g*128 + c, g = sh*2+sw  ->  out[b, 2y+sh, 2x+sw, c]
          const int g = o >> 7, c = o & 127;
          const int sh = g >> 1, sw = g & 1;
          OUT[(((size_t)(b * 128) + 2 * y + sh) * 128 + (2 * p + sw)) * 128 + c] = (TOUT)v;
        }
      }
    }
  }
}

extern "C" void kernel_launch(void* const* d_in, const int* in_sizes, int n_in,
                              void* d_out, int out_size, void* d_ws, size_t ws_size,
                              hipStream_t stream)
{
  const float* x   = (const float*)d_in[0];
  const float* w   = (const float*)d_in[1];
  const float* a1w = (const float*)d_in[2];
  const float* a1b = (const float*)d_in[3];
  const float* k1  = (const float*)d_in[4];
  const float* ns1 = (const float*)d_in[5];
  const float* b1  = (const float*)d_in[6];
  const float* a2w = (const float*)d_in[7];
  const float* a2b = (const float*)d_in[8];
  const float* k2  = (const float*)d_in[9];
  const float* ns2 = (const float*)d_in[10];
  const float* b2  = (const float*)d_in[11];
  const float* nz1 = (const float*)d_in[12];
  const float* nz2 = (const float*)d_in[13];
  float* out = (float*)d_out;

  float* ws = (float*)d_ws;
  float* s1   = ws;              // [16,256]
  float* s2   = ws + 4096;       // [16,256]
  float* ksq1 = ws + 8192;       // [256,256]
  float* ksq2 = ws + 73728;      // [256,512]
  float* dm1  = ws + 204800;     // [16,256]
  float* dm2  = ws + 208896;     // [16,512]
  _Float16* Bt1 = (_Float16*)(ws + 217088);  // [9,256,256] f16
  _Float16* Bt2 = Bt1 + 9 * 256 * 256;       // [9,512,256] f16
  _Float16* h   = Bt2 + 9 * 512 * 256;       // [16,64,64,256] f16

  style_kernel<<<16, 256, 0, stream>>>(w, a1w, a1b, a2w, a2b, s1, s2);
  ksq_kernel<<<65536 / 256, 256, 0, stream>>>(k1, ksq1, 65536);
  ksq_kernel<<<131072 / 256, 256, 0, stream>>>(k2, ksq2, 131072);
  demod_kernel<<<dim3(1, 16), 256, 0, stream>>>(s1, ksq1, dm1, 256);
  demod_kernel<<<dim3(2, 16), 256, 0, stream>>>(s2, ksq2, dm2, 512);
  kprep_kernel<<<dim3(4, 4, 9), 256, 0, stream>>>(k1, Bt1, 256);
  kprep_kernel<<<dim3(8, 4, 9), 256, 0, stream>>>(k2, Bt2, 512);

  conv_mfma<256, false, float, _Float16><<<dim3(1024, 4), 256, 0, stream>>>(
      x, s1, Bt1, dm1, nz1, ns1, b1, h);
  conv_mfma<512, true, _Float16, float><<<dim3(1024, 8), 256, 0, stream>>>(
      h, s2, Bt2, dm2, nz2, ns2, b2, out);
}

// Round 8
// 582.061 us; speedup vs baseline: 6.5868x; 1.1973x over previous
//
#include <hip/hip_runtime.h>
#include <type_traits>

// ---------------------------------------------------------------------------
// StyleGAN2 SynthesisBlock, MFMA f16, round 6 structure.
//   modconv(x, kernel, s) == demod[b,o] * conv2d(x * s[b,i], kernel)
//   demod[b,o] = rsqrt( sum_i s[b,i]^2 * ksq[i,o] + 1e-8 )
// conv1 epilogue writes h2m = lrelu(conv1..)*s2  (f16)  -> conv2 staging is a
// straight f16 copy (no modulate/convert in the hot loop).
// Block = 64 px row x 128 out-ch, 512 thr / 8 waves (2Mx4N), 16x16x32 f16 MFMA.
// Bijective XCD swizzle: contiguous rows per XCD -> dy-halo L2 reuse.
// ---------------------------------------------------------------------------

#define CIN 256

typedef _Float16 half4 __attribute__((ext_vector_type(4)));
typedef _Float16 half8 __attribute__((ext_vector_type(8)));
typedef float f32x4 __attribute__((ext_vector_type(4)));

__global__ __launch_bounds__(256) void style_kernel(
    const float* __restrict__ w, const float* __restrict__ a1w, const float* __restrict__ a1b,
    const float* __restrict__ a2w, const float* __restrict__ a2b,
    float* __restrict__ s1, float* __restrict__ s2)
{
  const int b = blockIdx.x, c = threadIdx.x;
  const float* wb = w + b * 128;
  float acc1 = 0.f, acc2 = 0.f;
  for (int k = 0; k < 128; ++k) {
    const float wv = wb[k];
    acc1 = fmaf(wv, a1w[k * 256 + c], acc1);
    acc2 = fmaf(wv, a2w[k * 256 + c], acc2);
  }
  s1[b * 256 + c] = acc1 + a1b[c];
  s2[b * 256 + c] = acc2 + a2b[c];
}

__global__ __launch_bounds__(256) void ksq_kernel(
    const float* __restrict__ kern, float* __restrict__ ksq, int n)
{
  const int i = blockIdx.x * 256 + threadIdx.x;
  if (i < n) {
    float acc = 0.f;
    for (int t = 0; t < 9; ++t) { const float v = kern[t * n + i]; acc = fmaf(v, v, acc); }
    ksq[i] = acc;
  }
}

__global__ __launch_bounds__(256) void demod_kernel(
    const float* __restrict__ s, const float* __restrict__ ksq,
    float* __restrict__ demod, int cout)
{
  const int b = blockIdx.y;
  const int o = blockIdx.x * 256 + threadIdx.x;
  const float* sb = s + b * 256;
  float acc = 1e-8f;
  for (int i = 0; i < 256; ++i) {
    const float sv = sb[i];
    acc = fmaf(sv * sv, ksq[i * cout + o], acc);
  }
  demod[b * cout + o] = 1.0f / sqrtf(acc);
}

// Kw[9][CIN][COUT] f32  ->  Bt[9][COUT][CIN] f16   (per-tap transpose + convert)
__global__ __launch_bounds__(256) void kprep_kernel(
    const float* __restrict__ Kw, _Float16* __restrict__ Bt, int cout)
{
  __shared__ float T[64][68];
  const int tap = blockIdx.z;
  const int o0 = blockIdx.x * 64, c0 = blockIdx.y * 64;
  const int t = threadIdx.x;
  #pragma unroll
  for (int it = 0; it < 4; ++it) {
    const int c = (t >> 4) + it * 16;
    const int o = (t & 15) * 4;
    *(float4*)(&T[c][o]) = *(const float4*)(Kw + ((size_t)tap * CIN + c0 + c) * cout + o0 + o);
  }
  __syncthreads();
  #pragma unroll
  for (int it = 0; it < 4; ++it) {
    const int o = (t >> 4) + it * 16;
    const int c = (t & 15) * 4;
    half4 hv = {(_Float16)T[c][o], (_Float16)T[c + 1][o],
                (_Float16)T[c + 2][o], (_Float16)T[c + 3][o]};
    *(half4*)(&Bt[((size_t)tap * cout + o0 + o) * CIN + c0 + c]) = hv;
  }
}

// MFMA implicit-GEMM modulated conv + fused epilogue.
// Block: M=64 px (one b,y row), N=128 out-ch. 8 waves (2Mx4N), wave = 32x32
// via 2x2 fragments of v_mfma_f32_16x16x32_f16.
// AMOD:    A-stage multiplies by style (f32 input);  else straight f16 copy.
// SHUFFLE: epilogue pixel-shuffles f32 out;  else writes f16 * SMOD[o] (h2m).
template <int COUT, bool AMOD, bool SHUFFLE, typename TIN, typename TOUT>
__global__ __launch_bounds__(512) void conv_mfma(
    const TIN* __restrict__ X,       // [16,64,64,256]
    const float* __restrict__ Sg,    // [16,256] style (AMOD only)
    const _Float16* __restrict__ Bt, // [9,COUT,256] f16
    const float* __restrict__ D,     // [16,COUT]
    const float* __restrict__ NZ,    // [16,64,64,1]
    const float* __restrict__ NSp,   // [1]
    const float* __restrict__ BIAS,  // [COUT]
    const float* __restrict__ SMOD,  // [16,256] s2 (epilogue mod, !SHUFFLE only)
    TOUT* __restrict__ OUT)
{
  __shared__ __align__(16) _Float16 As[66][72];       // halo rows xs=-1..64, +8 pad
  __shared__ __align__(16) _Float16 Bs[3][128][72];   // 3 dx taps

  const int t = threadIdx.x;
  // bijective XCD swizzle (nwg % 8 == 0): XCD k gets a contiguous wgid span.
  constexpr int nwg = (COUT / 128) * 1024;
  constexpr int q = nwg >> 3;
  const int lin = blockIdx.x;
  const int wgid = (lin & 7) * q + (lin >> 3);
  const int row = wgid & 1023, oc = wgid >> 10;   // same-XCD: contiguous rows
  const int b = row >> 6, y = row & 63;
  const int o0 = oc * 128;

  const int lane = t & 63, wid = t >> 6;
  const int wm = wid & 1, wn = wid >> 1;          // 2M x 4N wave grid
  const int lrow = lane >> 4;                     // k-octet / D row group
  const int lcol = lane & 15;

  // staging decomposition: 8 threads per row, half8 (16B) each
  const int sr = t >> 3;            // 0..63
  const int sco = (t & 7) * 8;      // 0..56

  f32x4 acc[2][2];
  #pragma unroll
  for (int m = 0; m < 2; ++m)
    #pragma unroll
    for (int n = 0; n < 2; ++n)
      acc[m][n] = (f32x4){0.f, 0.f, 0.f, 0.f};

  const TIN* Xb = X + (size_t)b * (64 * 64 * 256);

  for (int dyi = 0; dyi < 3; ++dyi) {
    const int ys = y + dyi - 1;
    const bool vrow = ((unsigned)ys < 64u);
    const TIN* Xrow = Xb + (size_t)(vrow ? ys : 0) * (64 * 256);

    for (int c0 = 0; c0 < 256; c0 += 64) {
      __syncthreads();  // protect previous chunk's fragment reads
      // ---- stage A: rows 0..63 by all threads, rows 64..65 by threads 0..15
      #pragma unroll
      for (int part = 0; part < 2; ++part) {
        const int r = part ? 64 + (t >> 3) : sr;
        if (part == 0 || t < 16) {
          const int xs = r - 1;
          const bool v = vrow && ((unsigned)xs < 64u);
          half8 hv = {(_Float16)0, (_Float16)0, (_Float16)0, (_Float16)0,
                      (_Float16)0, (_Float16)0, (_Float16)0, (_Float16)0};
          if (v) {
            if constexpr (AMOD) {
              const float4 x0 = *(const float4*)(Xrow + (size_t)xs * 256 + c0 + sco);
              const float4 x1 = *(const float4*)(Xrow + (size_t)xs * 256 + c0 + sco + 4);
              const float4 s0 = *(const float4*)(Sg + b * 256 + c0 + sco);
              const float4 s1v = *(const float4*)(Sg + b * 256 + c0 + sco + 4);
              hv[0] = (_Float16)(x0.x * s0.x);  hv[1] = (_Float16)(x0.y * s0.y);
              hv[2] = (_Float16)(x0.z * s0.z);  hv[3] = (_Float16)(x0.w * s0.w);
              hv[4] = (_Float16)(x1.x * s1v.x); hv[5] = (_Float16)(x1.y * s1v.y);
              hv[6] = (_Float16)(x1.z * s1v.z); hv[7] = (_Float16)(x1.w * s1v.w);
            } else {
              hv = *(const half8*)(Xrow + (size_t)xs * 256 + c0 + sco);
            }
          }
          *(half8*)(&As[r][sco]) = hv;
        }
      }
      // ---- stage B: 3 dx taps, Bs[dxi][n][k], straight f16 copy
      #pragma unroll
      for (int dxi = 0; dxi < 3; ++dxi) {
        const int tap = dyi * 3 + dxi;
        const _Float16* Bsrc = Bt + ((size_t)tap * COUT + o0) * 256 + c0;
        #pragma unroll
        for (int pass = 0; pass < 2; ++pass) {
          const int n = (t >> 3) + pass * 64;
          *(half8*)(&Bs[dxi][n][sco]) = *(const half8*)(Bsrc + (size_t)n * 256 + sco);
        }
      }
      __syncthreads();
      // ---- MFMA: 3 dx taps x 2 K-steps x (2x2 frags)
      #pragma unroll
      for (int dxi = 0; dxi < 3; ++dxi) {
        const int abase = dxi + wm * 32 + lcol;   // As row = p + dx + 1
        #pragma unroll
        for (int ks = 0; ks < 2; ++ks) {
          const int ko = ks * 32 + lrow * 8;
          const half8 a0 = *(const half8*)(&As[abase][ko]);
          const half8 a1 = *(const half8*)(&As[abase + 16][ko]);
          const half8 b0 = *(const half8*)(&Bs[dxi][wn * 32 + lcol][ko]);
          const half8 b1 = *(const half8*)(&Bs[dxi][wn * 32 + 16 + lcol][ko]);
          acc[0][0] = __builtin_amdgcn_mfma_f32_16x16x32_f16(a0, b0, acc[0][0], 0, 0, 0);
          acc[0][1] = __builtin_amdgcn_mfma_f32_16x16x32_f16(a0, b1, acc[0][1], 0, 0, 0);
          acc[1][0] = __builtin_amdgcn_mfma_f32_16x16x32_f16(a1, b0, acc[1][0], 0, 0, 0);
          acc[1][1] = __builtin_amdgcn_mfma_f32_16x16x32_f16(a1, b1, acc[1][1], 0, 0, 0);
        }
      }
    }
  }

  // ---- epilogue: D layout col = lane&15, row = (lane>>4)*4 + r  [m89-verified]
  const float ns = NSp[0];
  #pragma unroll
  for (int n = 0; n < 2; ++n) {
    const int o = o0 + wn * 32 + n * 16 + lcol;
    const float dmv = D[b * COUT + o];
    const float bv = BIAS[o];
    float smv = 1.0f;
    if constexpr (!SHUFFLE) smv = SMOD[b * 256 + o];
    #pragma unroll
    for (int m = 0; m < 2; ++m) {
      #pragma unroll
      for (int r = 0; r < 4; ++r) {
        const int p = wm * 32 + m * 16 + lrow * 4 + r;   // output x
        const float nzv = NZ[(size_t)(b * 64 + y) * 64 + p] * ns;
        float v = fmaf(acc[m][n][r], dmv, nzv + bv);
        v = fmaxf(v, 0.2f * v);                          // leaky_relu(0.2)
        if constexpr (!SHUFFLE) {
          // h2m = h * s2  (pre-modulated input for conv2)
          OUT[((size_t)(b * 64 + y) * 64 + p) * COUT + o] = (TOUT)(v * smv);
        } else {
          // o = g*128 + c, g = sh*2+sw  ->  out[b, 2y+sh, 2x+sw, c]
          const int g = o >> 7, c = o & 127;
          const int sh = g >> 1, sw = g & 1;
          OUT[(((size_t)(b * 128) + 2 * y + sh) * 128 + (2 * p + sw)) * 128 + c] = (TOUT)v;
        }
      }
    }
  }
}

extern "C" void kernel_launch(void* const* d_in, const int* in_sizes, int n_in,
                              void* d_out, int out_size, void* d_ws, size_t ws_size,
                              hipStream_t stream)
{
  const float* x   = (const float*)d_in[0];
  const float* w   = (const float*)d_in[1];
  const float* a1w = (const float*)d_in[2];
  const float* a1b = (const float*)d_in[3];
  const float* k1  = (const float*)d_in[4];
  const float* ns1 = (const float*)d_in[5];
  const float* b1  = (const float*)d_in[6];
  const float* a2w = (const float*)d_in[7];
  const float* a2b = (const float*)d_in[8];
  const float* k2  = (const float*)d_in[9];
  const float* ns2 = (const float*)d_in[10];
  const float* b2  = (const float*)d_in[11];
  const float* nz1 = (const float*)d_in[12];
  const float* nz2 = (const float*)d_in[13];
  float* out = (float*)d_out;

  float* ws = (float*)d_ws;
  float* s1   = ws;              // [16,256]
  float* s2   = ws + 4096;       // [16,256]
  float* ksq1 = ws + 8192;       // [256,256]
  float* ksq2 = ws + 73728;      // [256,512]
  float* dm1  = ws + 204800;     // [16,256]
  float* dm2  = ws + 208896;     // [16,512]
  _Float16* Bt1 = (_Float16*)(ws + 217088);  // [9,256,256] f16
  _Float16* Bt2 = Bt1 + 9 * 256 * 256;       // [9,512,256] f16
  _Float16* h2m = Bt2 + 9 * 512 * 256;       // [16,64,64,256] f16, = h * s2

  style_kernel<<<16, 256, 0, stream>>>(w, a1w, a1b, a2w, a2b, s1, s2);
  ksq_kernel<<<65536 / 256, 256, 0, stream>>>(k1, ksq1, 65536);
  ksq_kernel<<<131072 / 256, 256, 0, stream>>>(k2, ksq2, 131072);
  demod_kernel<<<dim3(1, 16), 256, 0, stream>>>(s1, ksq1, dm1, 256);
  demod_kernel<<<dim3(2, 16), 256, 0, stream>>>(s2, ksq2, dm2, 512);
  kprep_kernel<<<dim3(4, 4, 9), 256, 0, stream>>>(k1, Bt1, 256);
  kprep_kernel<<<dim3(8, 4, 9), 256, 0, stream>>>(k2, Bt2, 512);

  // conv1: modulated A (x * s1), epilogue writes h2m = lrelu(..) * s2 (f16)
  conv_mfma<256, true, false, float, _Float16><<<2048, 512, 0, stream>>>(
      x, s1, Bt1, dm1, nz1, ns1, b1, s2, h2m);
  // conv2: plain copy A (already modulated), epilogue pixel-shuffles f32 out
  conv_mfma<512, false, true, _Float16, float><<<4096, 512, 0, stream>>>(
      h2m, nullptr, Bt2, dm2, nz2, ns2, b2, nullptr, out);
}